// Round 4
// baseline (305.891 us; speedup 1.0000x reference)
//
#include <hip/hip_runtime.h>
#include <hip/hip_fp16.h>

// GCN 2-layer forward. N=100000 nodes, E=1600000 directed edges.
// out[c] = relu( dinv[c] * ( sum_{r->c} g[r] + g[c] ) + b ),  g = (x@W)*dinv
// dinv = rsqrt(indeg+1) (self-loops folded in analytically).
// Round 14: direct global counting sort replaces the two-phase bucket
// fill+sort (round 13 proved gathers are VMEM-line-bound, not divergence
// bound -> perm deleted; preprocessing was ~70us of the 153-161us total).
//   memset cnt -> hist (1.6M L2 atomics) -> per-bucket wave-scan (2 barriers,
//   fused mm1) -> scatter (srow written once, in final CSR order).
// Saves the full srow write+read+write round trip and the 16-barrier
// Hillis-Steele scan. Gathers are the proven round-10 form (no perm).

constexpr int NN  = 100000;
constexpr int FIN = 16;
constexpr int FH  = 32;   // hidden
constexpr int FO  = 16;   // layer-2 out

constexpr int BK      = 256;                     // nodes per bucket (scan granule)
constexpr int NBUCKET = (NN + BK - 1) / BK;      // 391
constexpr int CAP     = 5376;                    // bucket segment capacity (mean 4092, +20 sigma)

static __device__ __forceinline__ int pack2(float a, float b) {
    __half2 t = __float22half2_rn(make_float2(a, b));
    return *reinterpret_cast<int*>(&t);
}
static __device__ __forceinline__ float2 unpack2(int v) {
    __half2 t = *reinterpret_cast<__half2*>(&v);
    return __half22float2(t);
}

// ---- hist: cnt[c] += 1 per edge (cnt pre-zeroed by memset) ----
__global__ __launch_bounds__(256) void hist_kernel(
        const int* __restrict__ col, int* __restrict__ cnt, int E) {
    int tid = blockIdx.x * blockDim.x + threadIdx.x;
    int E4 = E >> 2;
    const int4* c4 = (const int4*)col;
    if (tid < E4) {
        int4 c = c4[tid];
        atomicAdd(&cnt[c.x], 1);
        atomicAdd(&cnt[c.y], 1);
        atomicAdd(&cnt[c.z], 1);
        atomicAdd(&cnt[c.w], 1);
    }
    if (tid == 0)
        for (int e = E4 << 2; e < E; e++) atomicAdd(&cnt[col[e]], 1);
}

// ---- scan_mm1: per-bucket exclusive scan of degrees (wave shfl scan, 2
// barriers) -> off/cursor; dinv; fused mm1 -> g1. 391 blocks x 256. ----
__global__ __launch_bounds__(256) void scan_mm1_kernel(
        const int* __restrict__ cnt, int* __restrict__ off,
        int* __restrict__ cursor, float* __restrict__ dinv,
        const float* __restrict__ x, const float* __restrict__ W1,
        __half* __restrict__ g1, int n) {
    __shared__ float w1[FIN * FH];
    __shared__ int wsum[4];
    __shared__ int wbase[4];
    int t = threadIdx.x;
    for (int i = t; i < FIN * FH; i += 256) w1[i] = W1[i];
    int lo = blockIdx.x << 8;
    int nodes = n - lo; if (nodes > BK) nodes = BK;
    int v = (t < nodes) ? cnt[lo + t] : 0;
    // inclusive scan within each 64-lane wave
    int s = v;
    #pragma unroll
    for (int d = 1; d < 64; d <<= 1) {
        int u = __shfl_up(s, d, 64);
        if ((t & 63) >= d) s += u;
    }
    if ((t & 63) == 63) wsum[t >> 6] = s;
    __syncthreads();
    if (t < 4) {
        int b = 0;
        for (int k = 0; k < t; k++) b += wsum[k];
        wbase[t] = b;
    }
    __syncthreads();
    int excl = s + wbase[t >> 6] - v;                  // exclusive prefix in bucket
    int s0 = blockIdx.x * CAP;
    float di = rsqrtf((float)v + 1.0f);
    if (t < nodes) {
        off[lo + t]    = s0 + excl;
        cursor[lo + t] = s0 + excl;
        dinv[lo + t]   = di;
    }
    __syncthreads();                                   // w1 loaded
    // ---- fused mm1: g1[lo+t] = fp16( (x[lo+t] @ W1) * di ) ----
    if (t < nodes) {
        int nd = lo + t;
        float xi[FIN];
        const float4* xv = (const float4*)(x + (long long)nd * FIN);
        #pragma unroll
        for (int i = 0; i < FIN / 4; i++) {
            float4 vv = xv[i];
            xi[4*i] = vv.x; xi[4*i+1] = vv.y; xi[4*i+2] = vv.z; xi[4*i+3] = vv.w;
        }
        float h[FH];
        #pragma unroll
        for (int j = 0; j < FH; j++) h[j] = 0.f;
        #pragma unroll
        for (int i = 0; i < FIN; i++) {
            float xs = xi[i];
            #pragma unroll
            for (int j = 0; j < FH; j++) h[j] += xs * w1[i * FH + j];
        }
        int4* gv = (int4*)(g1 + (long long)nd * FH);   // 64 B row
        #pragma unroll
        for (int k = 0; k < 4; k++) {
            gv[k] = make_int4(pack2(h[8*k]*di,   h[8*k+1]*di),
                              pack2(h[8*k+2]*di, h[8*k+3]*di),
                              pack2(h[8*k+4]*di, h[8*k+5]*di),
                              pack2(h[8*k+6]*di, h[8*k+7]*di));
        }
    }
}

// ---- scatter: srow[cursor[c]++] = r. Writes CSR order directly. ----
__global__ __launch_bounds__(256) void scatter_kernel(
        const int* __restrict__ row, const int* __restrict__ col,
        int* __restrict__ cursor, int* __restrict__ srow, int E) {
    int tid = blockIdx.x * blockDim.x + threadIdx.x;
    int E4 = E >> 2;
    const int4* c4 = (const int4*)col;
    const int4* r4 = (const int4*)row;
    if (tid < E4) {
        int4 c = c4[tid];
        int4 r = r4[tid];
        srow[atomicAdd(&cursor[c.x], 1)] = r.x;
        srow[atomicAdd(&cursor[c.y], 1)] = r.y;
        srow[atomicAdd(&cursor[c.z], 1)] = r.z;
        srow[atomicAdd(&cursor[c.w], 1)] = r.w;
    }
    if (tid == 0)
        for (int e = E4 << 2; e < E; e++)
            srow[atomicAdd(&cursor[col[e]], 1)] = row[e];
}

// ---- fused gather layer1 (fp16 rows) + relu/bias + mm2 + scale -> g2 (fp16) ----
// block = 256 threads = 64 nodes x 4 lanes (lane = 8 feats = int4 = 16 B)
constexpr int XS = 36;   // LDS stride: 16B-aligned writes, 2-way (free) reads
__global__ __launch_bounds__(256) void gather_mm2_kernel(
        const int* __restrict__ off, const int* __restrict__ cnt,
        const int* __restrict__ srow, const __half* __restrict__ g1,
        const float* __restrict__ dinv, const float* __restrict__ b1,
        const float* __restrict__ W2, __half* __restrict__ g2, int n) {
    __shared__ float xs[64 * XS];          // 64 nodes x 32 feats (stride 36)
    __shared__ float w[FH * FO];           // 32x16
    __shared__ float bb[FH];
    int t = threadIdx.x;
    for (int i = t; i < FH * FO; i += 256) w[i] = W2[i];
    if (t < FH) bb[t] = b1[t];
    int nl = t >> 2;                       // node-local 0..63
    int q = t & 3;                         // 8-feat group
    int node = blockIdx.x * 64 + nl;
    bool live = node < n;
    float acc[8] = {0.f,0.f,0.f,0.f,0.f,0.f,0.f,0.f};
    float di = 0.f;
    if (live) {
        di = dinv[node];
        {   // self-loop seed
            int4 raw = ((const int4*)(g1 + (long long)node * FH))[q];
            float2 f0 = unpack2(raw.x), f1 = unpack2(raw.y);
            float2 f2 = unpack2(raw.z), f3 = unpack2(raw.w);
            acc[0] = f0.x; acc[1] = f0.y; acc[2] = f1.x; acc[3] = f1.y;
            acc[4] = f2.x; acc[5] = f2.y; acc[6] = f3.x; acc[7] = f3.y;
        }
        int s = off[node];
        int m = cnt[node];
        int i = 0;
        for (; i + 3 < m; i += 4) {        // 4 indices then 4 16B rows in flight
            int r0 = srow[s + i];
            int r1 = srow[s + i + 1];
            int r2 = srow[s + i + 2];
            int r3 = srow[s + i + 3];
            int4 ra = ((const int4*)(g1 + (long long)r0 * FH))[q];
            int4 rb = ((const int4*)(g1 + (long long)r1 * FH))[q];
            int4 rc = ((const int4*)(g1 + (long long)r2 * FH))[q];
            int4 rd = ((const int4*)(g1 + (long long)r3 * FH))[q];
            float2 u;
            u = unpack2(ra.x); acc[0] += u.x; acc[1] += u.y;
            u = unpack2(ra.y); acc[2] += u.x; acc[3] += u.y;
            u = unpack2(ra.z); acc[4] += u.x; acc[5] += u.y;
            u = unpack2(ra.w); acc[6] += u.x; acc[7] += u.y;
            u = unpack2(rb.x); acc[0] += u.x; acc[1] += u.y;
            u = unpack2(rb.y); acc[2] += u.x; acc[3] += u.y;
            u = unpack2(rb.z); acc[4] += u.x; acc[5] += u.y;
            u = unpack2(rb.w); acc[6] += u.x; acc[7] += u.y;
            u = unpack2(rc.x); acc[0] += u.x; acc[1] += u.y;
            u = unpack2(rc.y); acc[2] += u.x; acc[3] += u.y;
            u = unpack2(rc.z); acc[4] += u.x; acc[5] += u.y;
            u = unpack2(rc.w); acc[6] += u.x; acc[7] += u.y;
            u = unpack2(rd.x); acc[0] += u.x; acc[1] += u.y;
            u = unpack2(rd.y); acc[2] += u.x; acc[3] += u.y;
            u = unpack2(rd.z); acc[4] += u.x; acc[5] += u.y;
            u = unpack2(rd.w); acc[6] += u.x; acc[7] += u.y;
        }
        for (; i < m; i++) {
            int r0 = srow[s + i];
            int4 ra = ((const int4*)(g1 + (long long)r0 * FH))[q];
            float2 u;
            u = unpack2(ra.x); acc[0] += u.x; acc[1] += u.y;
            u = unpack2(ra.y); acc[2] += u.x; acc[3] += u.y;
            u = unpack2(ra.z); acc[4] += u.x; acc[5] += u.y;
            u = unpack2(ra.w); acc[6] += u.x; acc[7] += u.y;
        }
    }
    __syncthreads();                       // w/bb loaded; also before xs write
    if (live) {
        // x1[8q..8q+7] = relu(acc*di + b1)
        float* xr = xs + nl * XS + 8 * q;
        #pragma unroll
        for (int j = 0; j < 8; j++) {
            float a = acc[j] * di + bb[8*q + j];
            xr[j] = a > 0.f ? a : 0.f;
        }
    }
    __syncthreads();
    if (live) {
        // lane q computes outputs k = 4q..4q+3 of x1 @ W2 (FO=16)
        const float* xr = xs + nl * XS;
        int k0 = 4 * q;
        float o0 = 0.f, o1 = 0.f, o2 = 0.f, o3 = 0.f;
        #pragma unroll
        for (int j = 0; j < FH; j++) {
            float xj = xr[j];
            const float* wr = w + j * FO + k0;
            o0 += xj * wr[0];
            o1 += xj * wr[1];
            o2 += xj * wr[2];
            o3 += xj * wr[3];
        }
        ((int2*)(g2 + (long long)node * FO))[q] =
            make_int2(pack2(o0 * di, o1 * di), pack2(o2 * di, o3 * di));
    }
}

// ---- fused gather layer2 (fp16 rows) + relu/bias + fc -> out ----
// block = 256 threads = 128 nodes x 2 lanes (lane = 8 feats = int4 = 16 B)
__global__ __launch_bounds__(256) void gather_fc_kernel(
        const int* __restrict__ off, const int* __restrict__ cnt,
        const int* __restrict__ srow, const __half* __restrict__ g2,
        const float* __restrict__ dinv, const float* __restrict__ b2,
        const float* __restrict__ fcW, const float* __restrict__ fcb,
        float* __restrict__ out, int n) {
    __shared__ float w[FO];
    __shared__ float bb[FO];
    __shared__ float fb;
    int t = threadIdx.x;
    if (t < FO) { w[t] = fcW[t]; bb[t] = b2[t]; }
    if (t == 0) fb = fcb[0];
    __syncthreads();
    int node = blockIdx.x * 128 + (t >> 1);
    int q = t & 1;
    if (node >= n) return;
    float di = dinv[node];
    float acc[8];
    {   // self-loop seed
        int4 raw = ((const int4*)(g2 + (long long)node * FO))[q];
        float2 f0 = unpack2(raw.x), f1 = unpack2(raw.y);
        float2 f2 = unpack2(raw.z), f3 = unpack2(raw.w);
        acc[0] = f0.x; acc[1] = f0.y; acc[2] = f1.x; acc[3] = f1.y;
        acc[4] = f2.x; acc[5] = f2.y; acc[6] = f3.x; acc[7] = f3.y;
    }
    int s = off[node];
    int m = cnt[node];
    int i = 0;
    for (; i + 3 < m; i += 4) {
        int r0 = srow[s + i];
        int r1 = srow[s + i + 1];
        int r2 = srow[s + i + 2];
        int r3 = srow[s + i + 3];
        int4 ra = ((const int4*)(g2 + (long long)r0 * FO))[q];
        int4 rb = ((const int4*)(g2 + (long long)r1 * FO))[q];
        int4 rc = ((const int4*)(g2 + (long long)r2 * FO))[q];
        int4 rd = ((const int4*)(g2 + (long long)r3 * FO))[q];
        float2 u;
        u = unpack2(ra.x); acc[0] += u.x; acc[1] += u.y;
        u = unpack2(ra.y); acc[2] += u.x; acc[3] += u.y;
        u = unpack2(ra.z); acc[4] += u.x; acc[5] += u.y;
        u = unpack2(ra.w); acc[6] += u.x; acc[7] += u.y;
        u = unpack2(rb.x); acc[0] += u.x; acc[1] += u.y;
        u = unpack2(rb.y); acc[2] += u.x; acc[3] += u.y;
        u = unpack2(rb.z); acc[4] += u.x; acc[5] += u.y;
        u = unpack2(rb.w); acc[6] += u.x; acc[7] += u.y;
        u = unpack2(rc.x); acc[0] += u.x; acc[1] += u.y;
        u = unpack2(rc.y); acc[2] += u.x; acc[3] += u.y;
        u = unpack2(rc.z); acc[4] += u.x; acc[5] += u.y;
        u = unpack2(rc.w); acc[6] += u.x; acc[7] += u.y;
        u = unpack2(rd.x); acc[0] += u.x; acc[1] += u.y;
        u = unpack2(rd.y); acc[2] += u.x; acc[3] += u.y;
        u = unpack2(rd.z); acc[4] += u.x; acc[5] += u.y;
        u = unpack2(rd.w); acc[6] += u.x; acc[7] += u.y;
    }
    for (; i < m; i++) {
        int r0 = srow[s + i];
        int4 ra = ((const int4*)(g2 + (long long)r0 * FO))[q];
        float2 u;
        u = unpack2(ra.x); acc[0] += u.x; acc[1] += u.y;
        u = unpack2(ra.y); acc[2] += u.x; acc[3] += u.y;
        u = unpack2(ra.z); acc[4] += u.x; acc[5] += u.y;
        u = unpack2(ra.w); acc[6] += u.x; acc[7] += u.y;
    }
    // x2 = relu(acc*di + b2[8q..]); partial dot with fcW
    float p = 0.f;
    #pragma unroll
    for (int j = 0; j < 8; j++) {
        float a = acc[j] * di + bb[8*q + j];
        p += (a > 0.f ? a : 0.f) * w[8*q + j];
    }
    p += __shfl_down(p, 1, 2);             // reduce the node's 2 lanes
    if (q == 0) out[node] = p + fb;
}

extern "C" void kernel_launch(void* const* d_in, const int* in_sizes, int n_in,
                              void* d_out, int out_size, void* d_ws, size_t ws_size,
                              hipStream_t stream) {
    const int*   edge = (const int*)d_in[0];        // [2, E] int32
    const float* x    = (const float*)d_in[1];      // [N, 16]
    const float* W1   = (const float*)d_in[2];      // [16, 32]
    const float* b1   = (const float*)d_in[3];      // [32]
    const float* W2   = (const float*)d_in[4];      // [32, 16]
    const float* b2   = (const float*)d_in[5];      // [16]
    const float* fcW  = (const float*)d_in[6];      // [16, 1]
    const float* fcb  = (const float*)d_in[7];      // [1]
    float* out = (float*)d_out;

    const int E = in_sizes[0] / 2;                  // 1600000
    const int n = NN;
    const int* row = edge;
    const int* col = edge + E;

    // workspace layout (4-byte units), regions 128-elem aligned:
    const size_t nA = (size_t)((n + 127) & ~127);
    char* wsb = (char*)d_ws;
    int*   cnt     = (int*)wsb;                     // n ints (per-node degree)
    int*   off     = cnt + nA;                      // n ints
    int*   cursor  = off + nA;                      // n ints (scatter cursors)
    float* dinv    = (float*)(cursor + nA);         // n floats
    int*   srow    = (int*)(dinv + nA);             // (NBUCKET+1)*CAP ints (+slack seg)
    int*   srowEnd = srow + (size_t)(NBUCKET + 1) * CAP;
    __half* g1     = (__half*)srowEnd;              // n*FH halfs (6.4 MB)
    __half* g2     = g1 + (size_t)n * FH;           // n*FO halfs (3.2 MB)

    const int B = 256;
    const int E4 = E >> 2;
    const int nEdgeBlocks = (E4 + B - 1) / B;       // 1563

    // 1. cnt = 0
    hipMemsetAsync(cnt, 0, (size_t)n * sizeof(int), stream);
    // 2. degree histogram
    hist_kernel<<<nEdgeBlocks, B, 0, stream>>>(col, cnt, E);
    // 3. per-bucket scan -> off/cursor/dinv + fused mm1 -> g1
    scan_mm1_kernel<<<NBUCKET, B, 0, stream>>>(cnt, off, cursor, dinv, x, W1, g1, n);
    // 4. scatter edges into CSR order
    scatter_kernel<<<nEdgeBlocks, B, 0, stream>>>(row, col, cursor, srow, E);
    // 5. fused gather1 + relu/bias + mm2 + scale -> g2   (64 nodes/block)
    gather_mm2_kernel<<<(n + 63) / 64, B, 0, stream>>>(off, cnt, srow, g1, dinv, b1, W2, g2, n);
    // 6. fused gather2 + relu/bias + fc -> out            (128 nodes/block)
    gather_fc_kernel<<<(n + 127) / 128, B, 0, stream>>>(off, cnt, srow, g2, dinv, b2, fcW, fcb, out, n);
}

// Round 5
// 209.404 us; speedup vs baseline: 1.4608x; 1.4608x over previous
//
#include <hip/hip_runtime.h>
#include <hip/hip_fp16.h>

// GCN 2-layer forward. N=100000 nodes, E=1600000 directed edges.
// out[c] = relu( dinv[c] * ( sum_{r->c} g[r] + g[c] ) + b ),  g = (x@W)*dinv
// dinv = rsqrt(indeg+1) (self-loops folded in analytically).
// Round 15: counting sort FUSED into gather1. Evidence so far: LDS-atomic
// accumulation dead (r11/12: 306us, latency-serialized); perm dead (r13:
// gathers are VMEM-line-bound, not divergence-bound); global counting
// scatter dead (r14: 130us, 17x HBM write amplification from 4B scattered
// writes across 8 non-coherent L2s). Bucket fill (contiguous per-block run
// reservation) is the proven phase-A; the standalone sort kernel was the
// remaining fat (~30us: srow re-read, 16-barrier Hillis-Steele, re-write).
// Now: fill(+global degree hist, r11-proven) -> mm1 (standalone, uses hist)
// -> sortgather_mm2: per 128-node bucket, LDS counting sort (2-barrier
// shfl_up wave scan) + gather straight from LDS-sorted indices + mm2 via
// 4-lane shfl_xor butterfly (no xs staging, no extra barriers); sorted
// segment written back once for gather_fc. gather_fc unchanged (round-10).

constexpr int NN  = 100000;
constexpr int FIN = 16;
constexpr int FH  = 32;   // hidden
constexpr int FO  = 16;   // layer-2 out

constexpr int BK      = 128;                     // nodes per bucket (col>>7)
constexpr int NBUCKET = (NN + BK - 1) / BK;      // 782
constexpr int CHUNK   = 8192;                    // edges per block (fill)
constexpr int CAP     = 2816;                    // bucket capacity (mean 2048, +17 sigma)

static __device__ __forceinline__ int pack2(float a, float b) {
    __half2 t = __float22half2_rn(make_float2(a, b));
    return *reinterpret_cast<int*>(&t);
}
static __device__ __forceinline__ float2 unpack2(int v) {
    __half2 t = *reinterpret_cast<__half2*>(&v);
    return __half22float2(t);
}

// ---- init: bcursor[b] = b*CAP ----
__global__ void init_kernel(int* __restrict__ bcursor) {
    int b = blockIdx.x * blockDim.x + threadIdx.x;
    if (b < NBUCKET) bcursor[b] = b * CAP;
}

// ---- phase A: bucket fill into fixed segments + global degree hist ----
__global__ __launch_bounds__(256) void bucket_fill_kernel(
        const int* __restrict__ row, const int* __restrict__ col,
        int* __restrict__ bcursor, int* __restrict__ srow,
        int* __restrict__ cnt, int E) {
    __shared__ int cbuf[CHUNK];          // col chunk cached: read global col once
    __shared__ int bcnt[NBUCKET];
    __shared__ int bcur[NBUCKET];
    int t = threadIdx.x;
    int e0 = blockIdx.x * CHUNK;
    int m = E - e0; if (m > CHUNK) m = CHUNK;
    for (int b = t; b < NBUCKET; b += 256) bcnt[b] = 0;
    __syncthreads();
    for (int i = t; i < m; i += 256) {
        int c = col[e0 + i];
        cbuf[i] = c;
        atomicAdd(&bcnt[c >> 7], 1);
        atomicAdd(&cnt[c], 1);           // global degree histogram (r11-proven cheap)
    }
    __syncthreads();
    for (int b = t; b < NBUCKET; b += 256) {
        int v = bcnt[b];
        bcur[b] = v ? atomicAdd(&bcursor[b], v) : 0;   // contiguous run for this block
    }
    __syncthreads();
    for (int i = t; i < m; i += 256) {
        int c = cbuf[i];
        int r = row[e0 + i];
        int b = c >> 7;
        int p = atomicAdd(&bcur[b], 1);
        if (p < (b + 1) * CAP)           // paranoia guard (17-sigma event)
            srow[p] = ((c & (BK - 1)) << 17) | r;      // pack (c_local, r); r < 2^17
    }
}

// ---- mm1: dinv = rsqrt(deg+1); g1 = fp16( (x @ W1) * dinv ) ----
__global__ __launch_bounds__(256) void mm1_kernel(
        const int* __restrict__ cnt, float* __restrict__ dinv,
        const float* __restrict__ x, const float* __restrict__ W1,
        __half* __restrict__ g1, int n) {
    __shared__ float w1[FIN * FH];
    int t = threadIdx.x;
    for (int i = t; i < FIN * FH; i += 256) w1[i] = W1[i];
    __syncthreads();
    int nd = blockIdx.x * 256 + t;
    if (nd >= n) return;
    float di = rsqrtf((float)cnt[nd] + 1.0f);
    dinv[nd] = di;
    float xi[FIN];
    const float4* xv = (const float4*)(x + (long long)nd * FIN);
    #pragma unroll
    for (int i = 0; i < FIN / 4; i++) {
        float4 vv = xv[i];
        xi[4*i] = vv.x; xi[4*i+1] = vv.y; xi[4*i+2] = vv.z; xi[4*i+3] = vv.w;
    }
    float h[FH];
    #pragma unroll
    for (int j = 0; j < FH; j++) h[j] = 0.f;
    #pragma unroll
    for (int i = 0; i < FIN; i++) {
        float xs = xi[i];
        #pragma unroll
        for (int j = 0; j < FH; j++) h[j] += xs * w1[i * FH + j];
    }
    int4* gv = (int4*)(g1 + (long long)nd * FH);   // 64 B row
    #pragma unroll
    for (int k = 0; k < 4; k++) {
        gv[k] = make_int4(pack2(h[8*k]*di,   h[8*k+1]*di),
                          pack2(h[8*k+2]*di, h[8*k+3]*di),
                          pack2(h[8*k+4]*di, h[8*k+5]*di),
                          pack2(h[8*k+6]*di, h[8*k+7]*di));
    }
}

// ---- fused: per-bucket LDS counting sort + gather1 + relu/bias + mm2 -> g2,
// sorted segment written back for gather_fc, off written for gather_fc.
// 512 threads = 128 nodes x 4 lanes; sort phases use all 512.
__global__ __launch_bounds__(512) void sortgather_mm2_kernel(
        const int* __restrict__ bcursor, int* __restrict__ srow,
        int* __restrict__ off,
        const __half* __restrict__ g1, const float* __restrict__ b1,
        const float* __restrict__ W2, __half* __restrict__ g2, int n) {
    __shared__ int ebuf[CAP];
    __shared__ int sorted[CAP];
    __shared__ int cnt2[BK];
    __shared__ int noff[BK];
    __shared__ int ncnt[BK];
    __shared__ float sdi[BK];
    __shared__ int wsum[2];
    __shared__ int wbase[2];
    __shared__ float w[FH * FO];
    __shared__ float bb[FH];
    int t = threadIdx.x;
    for (int i = t; i < FH * FO; i += 512) w[i] = W2[i];
    if (t < FH) bb[t] = b1[t];
    int b  = blockIdx.x;
    int lo = b << 7;
    int nodes = n - lo; if (nodes > BK) nodes = BK;
    int s0 = b * CAP;
    int m = bcursor[b] - s0;                 // edges in this bucket
    if (m > CAP) m = CAP;
    if (m < 0)  m = 0;
    for (int i = t; i < m; i += 512) ebuf[i] = srow[s0 + i];
    if (t < BK) cnt2[t] = 0;
    __syncthreads();
    for (int i = t; i < m; i += 512) atomicAdd(&cnt2[ebuf[i] >> 17], 1);
    __syncthreads();
    int v = 0, s = 0;
    if (t < BK) {                            // waves 0,1: wave shfl scan
        v = cnt2[t];
        s = v;
        #pragma unroll
        for (int d = 1; d < 64; d <<= 1) {
            int u = __shfl_up(s, d, 64);
            if ((t & 63) >= d) s += u;
        }
        if ((t & 63) == 63) wsum[t >> 6] = s;
    }
    __syncthreads();
    if (t < 2) wbase[t] = (t == 0) ? 0 : wsum[0];
    __syncthreads();
    if (t < BK) {
        int excl = s + wbase[t >> 6] - v;    // exclusive prefix in bucket
        noff[t] = excl;
        ncnt[t] = v;
        cnt2[t] = excl;                      // scatter cursor
        sdi[t]  = rsqrtf((float)v + 1.0f);
        if (t < nodes) off[lo + t] = s0 + excl;   // for gather_fc
    }
    __syncthreads();
    for (int i = t; i < m; i += 512) {
        int pv = ebuf[i];
        int p = atomicAdd(&cnt2[pv >> 17], 1);
        sorted[p] = pv & 0x1FFFF;
    }
    __syncthreads();
    for (int i = t; i < m; i += 512) srow[s0 + i] = sorted[i];  // for gather_fc
    // ---- gather + relu/bias + mm2 (shfl butterfly, no LDS staging) ----
    int nl = t >> 2;                         // node-local 0..127
    int q  = t & 3;                          // 8-feat group
    if (nl < nodes) {
        int node = lo + nl;
        float di = sdi[nl];
        float acc[8];
        {   // self-loop seed
            int4 raw = ((const int4*)(g1 + (long long)node * FH))[q];
            float2 f0 = unpack2(raw.x), f1 = unpack2(raw.y);
            float2 f2 = unpack2(raw.z), f3 = unpack2(raw.w);
            acc[0] = f0.x; acc[1] = f0.y; acc[2] = f1.x; acc[3] = f1.y;
            acc[4] = f2.x; acc[5] = f2.y; acc[6] = f3.x; acc[7] = f3.y;
        }
        int sA = noff[nl];
        int md = ncnt[nl];
        int i = 0;
        for (; i + 3 < md; i += 4) {         // 4 rows in flight; indices from LDS
            int r0 = sorted[sA + i];
            int r1 = sorted[sA + i + 1];
            int r2 = sorted[sA + i + 2];
            int r3 = sorted[sA + i + 3];
            int4 ra = ((const int4*)(g1 + (long long)r0 * FH))[q];
            int4 rb = ((const int4*)(g1 + (long long)r1 * FH))[q];
            int4 rc = ((const int4*)(g1 + (long long)r2 * FH))[q];
            int4 rd = ((const int4*)(g1 + (long long)r3 * FH))[q];
            float2 u;
            u = unpack2(ra.x); acc[0] += u.x; acc[1] += u.y;
            u = unpack2(ra.y); acc[2] += u.x; acc[3] += u.y;
            u = unpack2(ra.z); acc[4] += u.x; acc[5] += u.y;
            u = unpack2(ra.w); acc[6] += u.x; acc[7] += u.y;
            u = unpack2(rb.x); acc[0] += u.x; acc[1] += u.y;
            u = unpack2(rb.y); acc[2] += u.x; acc[3] += u.y;
            u = unpack2(rb.z); acc[4] += u.x; acc[5] += u.y;
            u = unpack2(rb.w); acc[6] += u.x; acc[7] += u.y;
            u = unpack2(rc.x); acc[0] += u.x; acc[1] += u.y;
            u = unpack2(rc.y); acc[2] += u.x; acc[3] += u.y;
            u = unpack2(rc.z); acc[4] += u.x; acc[5] += u.y;
            u = unpack2(rc.w); acc[6] += u.x; acc[7] += u.y;
            u = unpack2(rd.x); acc[0] += u.x; acc[1] += u.y;
            u = unpack2(rd.y); acc[2] += u.x; acc[3] += u.y;
            u = unpack2(rd.z); acc[4] += u.x; acc[5] += u.y;
            u = unpack2(rd.w); acc[6] += u.x; acc[7] += u.y;
        }
        for (; i < md; i++) {
            int r0 = sorted[sA + i];
            int4 ra = ((const int4*)(g1 + (long long)r0 * FH))[q];
            float2 u;
            u = unpack2(ra.x); acc[0] += u.x; acc[1] += u.y;
            u = unpack2(ra.y); acc[2] += u.x; acc[3] += u.y;
            u = unpack2(ra.z); acc[4] += u.x; acc[5] += u.y;
            u = unpack2(ra.w); acc[6] += u.x; acc[7] += u.y;
        }
        // x1 = relu(acc*di + b1); mm2 partials over this lane's 8 feats
        float o[FO];
        #pragma unroll
        for (int k = 0; k < FO; k++) o[k] = 0.f;
        #pragma unroll
        for (int j = 0; j < 8; j++) {
            float a = acc[j] * di + bb[8*q + j];
            float xj = a > 0.f ? a : 0.f;
            const float* wr = w + (8*q + j) * FO;
            #pragma unroll
            for (int k = 0; k < FO; k++) o[k] += xj * wr[k];
        }
        // butterfly-reduce across the node's 4 lanes (aligned within wave)
        #pragma unroll
        for (int k = 0; k < FO; k++) o[k] += __shfl_xor(o[k], 1);
        #pragma unroll
        for (int k = 0; k < FO; k++) o[k] += __shfl_xor(o[k], 2);
        ((int2*)(g2 + (long long)node * FO))[q] =
            make_int2(pack2(o[4*q] * di,   o[4*q+1] * di),
                      pack2(o[4*q+2] * di, o[4*q+3] * di));
    }
}

// ---- fused gather layer2 (fp16 rows) + relu/bias + fc -> out ----
// block = 256 threads = 128 nodes x 2 lanes (lane = 8 feats = int4 = 16 B)
__global__ __launch_bounds__(256) void gather_fc_kernel(
        const int* __restrict__ off, const int* __restrict__ cnt,
        const int* __restrict__ srow, const __half* __restrict__ g2,
        const float* __restrict__ dinv, const float* __restrict__ b2,
        const float* __restrict__ fcW, const float* __restrict__ fcb,
        float* __restrict__ out, int n) {
    __shared__ float w[FO];
    __shared__ float bb[FO];
    __shared__ float fb;
    int t = threadIdx.x;
    if (t < FO) { w[t] = fcW[t]; bb[t] = b2[t]; }
    if (t == 0) fb = fcb[0];
    __syncthreads();
    int node = blockIdx.x * 128 + (t >> 1);
    int q = t & 1;
    if (node >= n) return;
    float di = dinv[node];
    float acc[8];
    {   // self-loop seed
        int4 raw = ((const int4*)(g2 + (long long)node * FO))[q];
        float2 f0 = unpack2(raw.x), f1 = unpack2(raw.y);
        float2 f2 = unpack2(raw.z), f3 = unpack2(raw.w);
        acc[0] = f0.x; acc[1] = f0.y; acc[2] = f1.x; acc[3] = f1.y;
        acc[4] = f2.x; acc[5] = f2.y; acc[6] = f3.x; acc[7] = f3.y;
    }
    int s = off[node];
    int m = cnt[node];
    int i = 0;
    for (; i + 3 < m; i += 4) {
        int r0 = srow[s + i];
        int r1 = srow[s + i + 1];
        int r2 = srow[s + i + 2];
        int r3 = srow[s + i + 3];
        int4 ra = ((const int4*)(g2 + (long long)r0 * FO))[q];
        int4 rb = ((const int4*)(g2 + (long long)r1 * FO))[q];
        int4 rc = ((const int4*)(g2 + (long long)r2 * FO))[q];
        int4 rd = ((const int4*)(g2 + (long long)r3 * FO))[q];
        float2 u;
        u = unpack2(ra.x); acc[0] += u.x; acc[1] += u.y;
        u = unpack2(ra.y); acc[2] += u.x; acc[3] += u.y;
        u = unpack2(ra.z); acc[4] += u.x; acc[5] += u.y;
        u = unpack2(ra.w); acc[6] += u.x; acc[7] += u.y;
        u = unpack2(rb.x); acc[0] += u.x; acc[1] += u.y;
        u = unpack2(rb.y); acc[2] += u.x; acc[3] += u.y;
        u = unpack2(rb.z); acc[4] += u.x; acc[5] += u.y;
        u = unpack2(rb.w); acc[6] += u.x; acc[7] += u.y;
        u = unpack2(rc.x); acc[0] += u.x; acc[1] += u.y;
        u = unpack2(rc.y); acc[2] += u.x; acc[3] += u.y;
        u = unpack2(rc.z); acc[4] += u.x; acc[5] += u.y;
        u = unpack2(rc.w); acc[6] += u.x; acc[7] += u.y;
        u = unpack2(rd.x); acc[0] += u.x; acc[1] += u.y;
        u = unpack2(rd.y); acc[2] += u.x; acc[3] += u.y;
        u = unpack2(rd.z); acc[4] += u.x; acc[5] += u.y;
        u = unpack2(rd.w); acc[6] += u.x; acc[7] += u.y;
    }
    for (; i < m; i++) {
        int r0 = srow[s + i];
        int4 ra = ((const int4*)(g2 + (long long)r0 * FO))[q];
        float2 u;
        u = unpack2(ra.x); acc[0] += u.x; acc[1] += u.y;
        u = unpack2(ra.y); acc[2] += u.x; acc[3] += u.y;
        u = unpack2(ra.z); acc[4] += u.x; acc[5] += u.y;
        u = unpack2(ra.w); acc[6] += u.x; acc[7] += u.y;
    }
    // x2 = relu(acc*di + b2[8q..]); partial dot with fcW
    float p = 0.f;
    #pragma unroll
    for (int j = 0; j < 8; j++) {
        float a = acc[j] * di + bb[8*q + j];
        p += (a > 0.f ? a : 0.f) * w[8*q + j];
    }
    p += __shfl_down(p, 1, 2);             // reduce the node's 2 lanes
    if (q == 0) out[node] = p + fb;
}

extern "C" void kernel_launch(void* const* d_in, const int* in_sizes, int n_in,
                              void* d_out, int out_size, void* d_ws, size_t ws_size,
                              hipStream_t stream) {
    const int*   edge = (const int*)d_in[0];        // [2, E] int32
    const float* x    = (const float*)d_in[1];      // [N, 16]
    const float* W1   = (const float*)d_in[2];      // [16, 32]
    const float* b1   = (const float*)d_in[3];      // [32]
    const float* W2   = (const float*)d_in[4];      // [32, 16]
    const float* b2   = (const float*)d_in[5];      // [16]
    const float* fcW  = (const float*)d_in[6];      // [16, 1]
    const float* fcb  = (const float*)d_in[7];      // [1]
    float* out = (float*)d_out;

    const int E = in_sizes[0] / 2;                  // 1600000
    const int n = NN;
    const int* row = edge;
    const int* col = edge + E;

    // workspace layout (4-byte units), regions 128-elem aligned:
    const size_t nA = (size_t)((n + 127) & ~127);
    char* wsb = (char*)d_ws;
    int*   cnt     = (int*)wsb;                     // n ints (per-node indegree, hist)
    int*   off     = cnt + nA;                      // n ints (CSR offsets)
    float* dinv    = (float*)(off + nA);            // n floats
    int*   bcursor = (int*)(dinv + nA);             // NBUCKET ints (pad 1024)
    int*   srow    = bcursor + 1024;                // (NBUCKET+1)*CAP ints (+slack seg)
    int*   srowEnd = srow + (size_t)(NBUCKET + 1) * CAP;
    __half* g1     = (__half*)srowEnd;              // n*FH halfs (6.4 MB)
    __half* g2     = g1 + (size_t)n * FH;           // n*FO halfs (3.2 MB)

    const int B = 256;
    const int nChunkBlocks = (E + CHUNK - 1) / CHUNK;   // 196

    // 1. cnt = 0; bcursor[b] = b*CAP
    hipMemsetAsync(cnt, 0, (size_t)n * sizeof(int), stream);
    init_kernel<<<(NBUCKET + B - 1) / B, B, 0, stream>>>(bcursor);
    // 2. bucket fill (unsorted, coalesced run reservation) + degree hist
    bucket_fill_kernel<<<nChunkBlocks, B, 0, stream>>>(row, col, bcursor, srow, cnt, E);
    // 3. dinv + mm1 -> g1  (degrees from hist)
    mm1_kernel<<<(n + B - 1) / B, B, 0, stream>>>(cnt, dinv, x, W1, g1, n);
    // 4. fused LDS sort + gather1 + relu/bias + mm2 -> g2; writes off + sorted srow
    sortgather_mm2_kernel<<<NBUCKET, 512, 0, stream>>>(bcursor, srow, off, g1, b1, W2, g2, n);
    // 5. fused gather2 + relu/bias + fc -> out  (128 nodes/block)
    gather_fc_kernel<<<(n + 127) / 128, B, 0, stream>>>(off, cnt, srow, g2, dinv, b2, fcW, fcb, out, n);
}

// Round 6
// 152.655 us; speedup vs baseline: 2.0038x; 1.3718x over previous
//
#include <hip/hip_runtime.h>
#include <hip/hip_fp16.h>

// GCN 2-layer forward. N=100000 nodes, E=1600000 directed edges.
// out[c] = relu( dinv[c] * ( sum_{r->c} g[r] + g[c] ) + b ),  g = (x@W)*dinv
// dinv = rsqrt(indeg+1) (self-loops folded in analytically).
// Round 16: byte-exact revert to the proven 153.5us round-10 kernel with ONE
// patch: the sort kernel's 16-barrier Hillis-Steele scan is replaced by a
// 2-barrier __shfl_up wave scan (proven correct in round-14's scan_mm1 at
// BK=256). Negative results bank (do NOT retry): LDS-atomic accumulation
// (r11/12: 306us, latency-serialized, CAS==ds_add_f32); degree-ranked perm
// (r13: gathers VMEM-line-bound, not divergence-bound); global counting
// scatter (r14: 130us, 17x HBM write amp from 4B scattered writes);
// 32KB cbuf in fill / NBUCKET=782 (r15: fill 87us, occupancy 7.8%, 42B-run
// write amp 10x).

constexpr int NN  = 100000;
constexpr int FIN = 16;
constexpr int FH  = 32;   // hidden
constexpr int FO  = 16;   // layer-2 out

constexpr int BK      = 256;                     // nodes per bucket (col>>8)
constexpr int NBUCKET = (NN + BK - 1) / BK;      // 391
constexpr int CHUNK   = 8192;                    // edges per block (fill)
constexpr int CAP     = 5376;                    // bucket segment capacity (mean 4092, +20 sigma)

static __device__ __forceinline__ int pack2(float a, float b) {
    __half2 t = __float22half2_rn(make_float2(a, b));
    return *reinterpret_cast<int*>(&t);
}
static __device__ __forceinline__ float2 unpack2(int v) {
    __half2 t = *reinterpret_cast<__half2*>(&v);
    return __half22float2(t);
}

// ---- init: bcursor[b] = b*CAP ----
__global__ void init_kernel(int* __restrict__ bcursor) {
    int b = blockIdx.x * blockDim.x + threadIdx.x;
    if (b < NBUCKET) bcursor[b] = b * CAP;
}

// ---- phase A: bucket fill into fixed segments. Per-block run reservation. ----
__global__ __launch_bounds__(256) void bucket_fill_kernel(
        const int* __restrict__ row, const int* __restrict__ col,
        int* __restrict__ bcursor, int* __restrict__ srow, int E) {
    __shared__ int bcnt[NBUCKET];
    __shared__ int bcur[NBUCKET];
    int t = threadIdx.x;
    int e0 = blockIdx.x * CHUNK;
    int m = E - e0; if (m > CHUNK) m = CHUNK;
    for (int b = t; b < NBUCKET; b += 256) bcnt[b] = 0;
    __syncthreads();
    for (int i = t; i < m; i += 256)
        atomicAdd(&bcnt[col[e0 + i] >> 8], 1);
    __syncthreads();
    for (int b = t; b < NBUCKET; b += 256) {
        int v = bcnt[b];
        bcur[b] = v ? atomicAdd(&bcursor[b], v) : 0;   // contiguous run for this block
    }
    __syncthreads();
    for (int i = t; i < m; i += 256) {
        int c = col[e0 + i];
        int r = row[e0 + i];
        int p = atomicAdd(&bcur[c >> 8], 1);
        srow[p] = ((c & (BK - 1)) << 17) | r;          // pack (c_local, r); r < 2^17
    }
}

// ---- phase B: per-bucket LDS counting sort; emits off/cnt/dinv AND g1 rows
// (mm1 fused: thread t owns node lo+t, its degree v is already in-register).
// Scan: 2-barrier shfl_up wave scan (round-14-proven), not Hillis-Steele.
__global__ __launch_bounds__(256) void bucket_sort_mm1_kernel(
        const int* __restrict__ bcursor, int* __restrict__ srow,
        int* __restrict__ off, int* __restrict__ cnt, float* __restrict__ dinv,
        const float* __restrict__ x, const float* __restrict__ W1,
        __half* __restrict__ g1, int n) {
    __shared__ int ebuf[CAP];
    __shared__ int sorted[CAP];
    __shared__ int cnt2[BK];
    __shared__ int wsum[4];
    __shared__ int wbase[4];
    __shared__ float w1[FIN * FH];
    int t = threadIdx.x;
    for (int i = t; i < FIN * FH; i += 256) w1[i] = W1[i];
    int lo = blockIdx.x << 8;
    int nodes = n - lo; if (nodes > BK) nodes = BK;
    int s0 = blockIdx.x * CAP;
    int m = bcursor[blockIdx.x] - s0;                  // total edges in this bucket
    if (m > CAP) m = CAP;                              // paranoia guard (never hit)
    for (int i = t; i < m; i += 256) ebuf[i] = srow[s0 + i];
    cnt2[t] = 0;
    __syncthreads();
    for (int i = t; i < m; i += 256) atomicAdd(&cnt2[ebuf[i] >> 17], 1);
    __syncthreads();
    int v = cnt2[t];
    // inclusive scan within each 64-lane wave (2 barriers total, no LDS aux)
    int s = v;
    #pragma unroll
    for (int d = 1; d < 64; d <<= 1) {
        int u = __shfl_up(s, d, 64);
        if ((t & 63) >= d) s += u;
    }
    if ((t & 63) == 63) wsum[t >> 6] = s;
    __syncthreads();
    if (t < 4) {
        int b = 0;
        for (int k = 0; k < t; k++) b += wsum[k];
        wbase[t] = b;
    }
    __syncthreads();
    int excl = s + wbase[t >> 6] - v;                  // exclusive prefix in bucket
    cnt2[t] = excl;                                    // cursor for scatter
    float di = rsqrtf((float)v + 1.0f);
    if (t < nodes) {                                   // per-node CSR metadata, free
        off[lo + t]  = s0 + excl;
        cnt[lo + t]  = v;
        dinv[lo + t] = di;
    }
    __syncthreads();
    for (int i = t; i < m; i += 256) {
        int pv = ebuf[i];
        int p = atomicAdd(&cnt2[pv >> 17], 1);
        sorted[p] = pv & 0x1FFFF;
    }
    __syncthreads();
    for (int i = t; i < m; i += 256) srow[s0 + i] = sorted[i];
    // ---- fused mm1: g1[lo+t] = fp16( (x[lo+t] @ W1) * di ) ----
    if (t < nodes) {
        int nd = lo + t;
        float xi[FIN];
        const float4* xv = (const float4*)(x + (long long)nd * FIN);
        #pragma unroll
        for (int i = 0; i < FIN / 4; i++) {
            float4 vv = xv[i];
            xi[4*i] = vv.x; xi[4*i+1] = vv.y; xi[4*i+2] = vv.z; xi[4*i+3] = vv.w;
        }
        float h[FH];
        #pragma unroll
        for (int j = 0; j < FH; j++) h[j] = 0.f;
        #pragma unroll
        for (int i = 0; i < FIN; i++) {
            float xs = xi[i];
            #pragma unroll
            for (int j = 0; j < FH; j++) h[j] += xs * w1[i * FH + j];
        }
        int4* gv = (int4*)(g1 + (long long)nd * FH);   // 64 B row
        #pragma unroll
        for (int k = 0; k < 4; k++) {
            gv[k] = make_int4(pack2(h[8*k]*di,   h[8*k+1]*di),
                              pack2(h[8*k+2]*di, h[8*k+3]*di),
                              pack2(h[8*k+4]*di, h[8*k+5]*di),
                              pack2(h[8*k+6]*di, h[8*k+7]*di));
        }
    }
}

// ---- fused gather layer1 (fp16 rows) + relu/bias + mm2 + scale -> g2 (fp16) ----
// block = 256 threads = 64 nodes x 4 lanes (lane = 8 feats = int4 = 16 B)
constexpr int XS = 36;   // LDS stride: 16B-aligned writes, 2-way (free) reads
__global__ __launch_bounds__(256) void gather_mm2_kernel(
        const int* __restrict__ off, const int* __restrict__ cnt,
        const int* __restrict__ srow, const __half* __restrict__ g1,
        const float* __restrict__ dinv, const float* __restrict__ b1,
        const float* __restrict__ W2, __half* __restrict__ g2, int n) {
    __shared__ float xs[64 * XS];          // 64 nodes x 32 feats (stride 36)
    __shared__ float w[FH * FO];           // 32x16
    __shared__ float bb[FH];
    int t = threadIdx.x;
    for (int i = t; i < FH * FO; i += 256) w[i] = W2[i];
    if (t < FH) bb[t] = b1[t];
    int nl = t >> 2;                       // node-local 0..63
    int q = t & 3;                         // 8-feat group
    int node = blockIdx.x * 64 + nl;
    bool live = node < n;
    float acc[8] = {0.f,0.f,0.f,0.f,0.f,0.f,0.f,0.f};
    float di = 0.f;
    if (live) {
        di = dinv[node];
        {   // self-loop seed
            int4 raw = ((const int4*)(g1 + (long long)node * FH))[q];
            float2 f0 = unpack2(raw.x), f1 = unpack2(raw.y);
            float2 f2 = unpack2(raw.z), f3 = unpack2(raw.w);
            acc[0] = f0.x; acc[1] = f0.y; acc[2] = f1.x; acc[3] = f1.y;
            acc[4] = f2.x; acc[5] = f2.y; acc[6] = f3.x; acc[7] = f3.y;
        }
        int s = off[node];
        int m = cnt[node];
        int i = 0;
        for (; i + 3 < m; i += 4) {        // 4 indices then 4 16B rows in flight
            int r0 = srow[s + i];
            int r1 = srow[s + i + 1];
            int r2 = srow[s + i + 2];
            int r3 = srow[s + i + 3];
            int4 ra = ((const int4*)(g1 + (long long)r0 * FH))[q];
            int4 rb = ((const int4*)(g1 + (long long)r1 * FH))[q];
            int4 rc = ((const int4*)(g1 + (long long)r2 * FH))[q];
            int4 rd = ((const int4*)(g1 + (long long)r3 * FH))[q];
            float2 u;
            u = unpack2(ra.x); acc[0] += u.x; acc[1] += u.y;
            u = unpack2(ra.y); acc[2] += u.x; acc[3] += u.y;
            u = unpack2(ra.z); acc[4] += u.x; acc[5] += u.y;
            u = unpack2(ra.w); acc[6] += u.x; acc[7] += u.y;
            u = unpack2(rb.x); acc[0] += u.x; acc[1] += u.y;
            u = unpack2(rb.y); acc[2] += u.x; acc[3] += u.y;
            u = unpack2(rb.z); acc[4] += u.x; acc[5] += u.y;
            u = unpack2(rb.w); acc[6] += u.x; acc[7] += u.y;
            u = unpack2(rc.x); acc[0] += u.x; acc[1] += u.y;
            u = unpack2(rc.y); acc[2] += u.x; acc[3] += u.y;
            u = unpack2(rc.z); acc[4] += u.x; acc[5] += u.y;
            u = unpack2(rc.w); acc[6] += u.x; acc[7] += u.y;
            u = unpack2(rd.x); acc[0] += u.x; acc[1] += u.y;
            u = unpack2(rd.y); acc[2] += u.x; acc[3] += u.y;
            u = unpack2(rd.z); acc[4] += u.x; acc[5] += u.y;
            u = unpack2(rd.w); acc[6] += u.x; acc[7] += u.y;
        }
        for (; i < m; i++) {
            int r0 = srow[s + i];
            int4 ra = ((const int4*)(g1 + (long long)r0 * FH))[q];
            float2 u;
            u = unpack2(ra.x); acc[0] += u.x; acc[1] += u.y;
            u = unpack2(ra.y); acc[2] += u.x; acc[3] += u.y;
            u = unpack2(ra.z); acc[4] += u.x; acc[5] += u.y;
            u = unpack2(ra.w); acc[6] += u.x; acc[7] += u.y;
        }
    }
    __syncthreads();                       // w/bb loaded; also before xs write
    if (live) {
        // x1[8q..8q+7] = relu(acc*di + b1)
        float* xr = xs + nl * XS + 8 * q;
        #pragma unroll
        for (int j = 0; j < 8; j++) {
            float a = acc[j] * di + bb[8*q + j];
            xr[j] = a > 0.f ? a : 0.f;
        }
    }
    __syncthreads();
    if (live) {
        // lane q computes outputs k = 4q..4q+3 of x1 @ W2 (FO=16)
        const float* xr = xs + nl * XS;
        int k0 = 4 * q;
        float o0 = 0.f, o1 = 0.f, o2 = 0.f, o3 = 0.f;
        #pragma unroll
        for (int j = 0; j < FH; j++) {
            float xj = xr[j];
            const float* wr = w + j * FO + k0;
            o0 += xj * wr[0];
            o1 += xj * wr[1];
            o2 += xj * wr[2];
            o3 += xj * wr[3];
        }
        ((int2*)(g2 + (long long)node * FO))[q] =
            make_int2(pack2(o0 * di, o1 * di), pack2(o2 * di, o3 * di));
    }
}

// ---- fused gather layer2 (fp16 rows) + relu/bias + fc -> out ----
// block = 256 threads = 128 nodes x 2 lanes (lane = 8 feats = int4 = 16 B)
__global__ __launch_bounds__(256) void gather_fc_kernel(
        const int* __restrict__ off, const int* __restrict__ cnt,
        const int* __restrict__ srow, const __half* __restrict__ g2,
        const float* __restrict__ dinv, const float* __restrict__ b2,
        const float* __restrict__ fcW, const float* __restrict__ fcb,
        float* __restrict__ out, int n) {
    __shared__ float w[FO];
    __shared__ float bb[FO];
    __shared__ float fb;
    int t = threadIdx.x;
    if (t < FO) { w[t] = fcW[t]; bb[t] = b2[t]; }
    if (t == 0) fb = fcb[0];
    __syncthreads();
    int node = blockIdx.x * 128 + (t >> 1);
    int q = t & 1;
    if (node >= n) return;
    float di = dinv[node];
    float acc[8];
    {   // self-loop seed
        int4 raw = ((const int4*)(g2 + (long long)node * FO))[q];
        float2 f0 = unpack2(raw.x), f1 = unpack2(raw.y);
        float2 f2 = unpack2(raw.z), f3 = unpack2(raw.w);
        acc[0] = f0.x; acc[1] = f0.y; acc[2] = f1.x; acc[3] = f1.y;
        acc[4] = f2.x; acc[5] = f2.y; acc[6] = f3.x; acc[7] = f3.y;
    }
    int s = off[node];
    int m = cnt[node];
    int i = 0;
    for (; i + 3 < m; i += 4) {
        int r0 = srow[s + i];
        int r1 = srow[s + i + 1];
        int r2 = srow[s + i + 2];
        int r3 = srow[s + i + 3];
        int4 ra = ((const int4*)(g2 + (long long)r0 * FO))[q];
        int4 rb = ((const int4*)(g2 + (long long)r1 * FO))[q];
        int4 rc = ((const int4*)(g2 + (long long)r2 * FO))[q];
        int4 rd = ((const int4*)(g2 + (long long)r3 * FO))[q];
        float2 u;
        u = unpack2(ra.x); acc[0] += u.x; acc[1] += u.y;
        u = unpack2(ra.y); acc[2] += u.x; acc[3] += u.y;
        u = unpack2(ra.z); acc[4] += u.x; acc[5] += u.y;
        u = unpack2(ra.w); acc[6] += u.x; acc[7] += u.y;
        u = unpack2(rb.x); acc[0] += u.x; acc[1] += u.y;
        u = unpack2(rb.y); acc[2] += u.x; acc[3] += u.y;
        u = unpack2(rb.z); acc[4] += u.x; acc[5] += u.y;
        u = unpack2(rb.w); acc[6] += u.x; acc[7] += u.y;
        u = unpack2(rc.x); acc[0] += u.x; acc[1] += u.y;
        u = unpack2(rc.y); acc[2] += u.x; acc[3] += u.y;
        u = unpack2(rc.z); acc[4] += u.x; acc[5] += u.y;
        u = unpack2(rc.w); acc[6] += u.x; acc[7] += u.y;
        u = unpack2(rd.x); acc[0] += u.x; acc[1] += u.y;
        u = unpack2(rd.y); acc[2] += u.x; acc[3] += u.y;
        u = unpack2(rd.z); acc[4] += u.x; acc[5] += u.y;
        u = unpack2(rd.w); acc[6] += u.x; acc[7] += u.y;
    }
    for (; i < m; i++) {
        int r0 = srow[s + i];
        int4 ra = ((const int4*)(g2 + (long long)r0 * FO))[q];
        float2 u;
        u = unpack2(ra.x); acc[0] += u.x; acc[1] += u.y;
        u = unpack2(ra.y); acc[2] += u.x; acc[3] += u.y;
        u = unpack2(ra.z); acc[4] += u.x; acc[5] += u.y;
        u = unpack2(ra.w); acc[6] += u.x; acc[7] += u.y;
    }
    // x2 = relu(acc*di + b2[8q..]); partial dot with fcW
    float p = 0.f;
    #pragma unroll
    for (int j = 0; j < 8; j++) {
        float a = acc[j] * di + bb[8*q + j];
        p += (a > 0.f ? a : 0.f) * w[8*q + j];
    }
    p += __shfl_down(p, 1, 2);             // reduce the node's 2 lanes
    if (q == 0) out[node] = p + fb;
}

extern "C" void kernel_launch(void* const* d_in, const int* in_sizes, int n_in,
                              void* d_out, int out_size, void* d_ws, size_t ws_size,
                              hipStream_t stream) {
    const int*   edge = (const int*)d_in[0];        // [2, E] int32
    const float* x    = (const float*)d_in[1];      // [N, 16]
    const float* W1   = (const float*)d_in[2];      // [16, 32]
    const float* b1   = (const float*)d_in[3];      // [32]
    const float* W2   = (const float*)d_in[4];      // [32, 16]
    const float* b2   = (const float*)d_in[5];      // [16]
    const float* fcW  = (const float*)d_in[6];      // [16, 1]
    const float* fcb  = (const float*)d_in[7];      // [1]
    float* out = (float*)d_out;

    const int E = in_sizes[0] / 2;                  // 1600000
    const int n = NN;
    const int* row = edge;
    const int* col = edge + E;

    // workspace layout (4-byte units), regions 128-elem aligned:
    const size_t nA = (size_t)((n + 127) & ~127);
    char* wsb = (char*)d_ws;
    int*   cnt     = (int*)wsb;                     // n ints (per-node degree)
    int*   off     = cnt + nA;                      // n ints
    float* dinv    = (float*)(off + nA);            // n floats
    int*   bcursor = (int*)(dinv + nA);             // NBUCKET ints (pad 512)
    int*   srow    = bcursor + 512;                 // (NBUCKET+1)*CAP ints (+slack seg)
    int*   srowEnd = srow + (size_t)(NBUCKET + 1) * CAP;
    __half* g1     = (__half*)srowEnd;              // n*FH halfs (6.4 MB)
    __half* g2     = g1 + (size_t)n * FH;           // n*FO halfs (3.2 MB)

    const int B = 256;
    const int nChunkBlocks = (E + CHUNK - 1) / CHUNK;   // 196

    // 1. bcursor[b] = b*CAP
    init_kernel<<<2, B, 0, stream>>>(bcursor);
    // 2. phase A: bucket fill into fixed segments; per-block run reservation
    bucket_fill_kernel<<<nChunkBlocks, B, 0, stream>>>(row, col, bcursor, srow, E);
    // 3. phase B: per-bucket LDS counting sort (2-barrier wave scan) + fused mm1
    bucket_sort_mm1_kernel<<<NBUCKET, B, 0, stream>>>(bcursor, srow, off, cnt, dinv, x, W1, g1, n);
    // 4. fused gather1 + relu/bias + mm2 + scale -> g2   (64 nodes/block)
    gather_mm2_kernel<<<(n + 63) / 64, B, 0, stream>>>(off, cnt, srow, g1, dinv, b1, W2, g2, n);
    // 5. fused gather2 + relu/bias + fc -> out            (128 nodes/block)
    gather_fc_kernel<<<(n + 127) / 128, B, 0, stream>>>(off, cnt, srow, g2, dinv, b2, fcW, fcb, out, n);
}

// Round 7
// 145.491 us; speedup vs baseline: 2.1025x; 1.0492x over previous
//
#include <hip/hip_runtime.h>
#include <hip/hip_fp16.h>

// GCN 2-layer forward. N=100000 nodes, E=1600000 directed edges.
// out[c] = relu( dinv[c] * ( sum_{r->c} g[r] + g[c] ) + b ),  g = (x@W)*dinv
// dinv = rsqrt(indeg+1) (self-loops folded in analytically).
// Round 17: three local fixes on the proven 152.6us structure.
//  (a) fill at 512 threads: was 196 blocks x 4 waves = 9.6% occupancy; run
//      reservation/write pattern unchanged (r15's regression was the 32KB
//      cbuf + NBUCKET=782, NOT thread count).
//  (b) sort at 512 threads (19%->38% occupancy); fused mm1 split across the
//      two half-blocks by feature-half; scan stays the 2-barrier shfl form.
//  (c) CSR segments padded to multiples of 4 with sentinel index NN whose
//      g1/g2 row is all zeros: gather index loads become one aligned int4
//      per 4 edges and the scalar tail loop disappears. +0.0f is exact ->
//      output bit-identical.
// Negative results bank (do NOT retry): LDS-atomic accumulation (r11/12);
// degree-ranked perm (r13); global counting scatter (r14: 17x write amp);
// 32KB col cache in fill / NBUCKET=782 (r15).

constexpr int NN  = 100000;
constexpr int FIN = 16;
constexpr int FH  = 32;   // hidden
constexpr int FO  = 16;   // layer-2 out

constexpr int BK      = 256;                     // nodes per bucket (col>>8)
constexpr int NBUCKET = (NN + BK - 1) / BK;      // 391
constexpr int CHUNK   = 8192;                    // edges per block (fill)
constexpr int CAP     = 5632;                    // bucket capacity (mean 4092 + pad<=768, +18 sigma)

static __device__ __forceinline__ int pack2(float a, float b) {
    __half2 t = __float22half2_rn(make_float2(a, b));
    return *reinterpret_cast<int*>(&t);
}
static __device__ __forceinline__ float2 unpack2(int v) {
    __half2 t = *reinterpret_cast<__half2*>(&v);
    return __half22float2(t);
}

// ---- init: bcursor[b] = b*CAP; zero sentinel rows g1[NN], g2[NN] ----
__global__ void init_kernel(int* __restrict__ bcursor,
                            __half* __restrict__ g1, __half* __restrict__ g2) {
    int b = blockIdx.x * blockDim.x + threadIdx.x;
    if (b < NBUCKET) bcursor[b] = b * CAP;
    if (b < 4) ((int4*)(g1 + (long long)NN * FH))[b] = make_int4(0, 0, 0, 0);
    else if (b < 6) ((int4*)(g2 + (long long)NN * FO))[b - 4] = make_int4(0, 0, 0, 0);
}

// ---- phase A: bucket fill into fixed segments. Per-block run reservation. ----
__global__ __launch_bounds__(512) void bucket_fill_kernel(
        const int* __restrict__ row, const int* __restrict__ col,
        int* __restrict__ bcursor, int* __restrict__ srow, int E) {
    __shared__ int bcnt[NBUCKET];
    __shared__ int bcur[NBUCKET];
    int t = threadIdx.x;
    int e0 = blockIdx.x * CHUNK;
    int m = E - e0; if (m > CHUNK) m = CHUNK;
    for (int b = t; b < NBUCKET; b += 512) bcnt[b] = 0;
    __syncthreads();
    for (int i = t; i < m; i += 512)
        atomicAdd(&bcnt[col[e0 + i] >> 8], 1);
    __syncthreads();
    for (int b = t; b < NBUCKET; b += 512) {
        int v = bcnt[b];
        bcur[b] = v ? atomicAdd(&bcursor[b], v) : 0;   // contiguous run for this block
    }
    __syncthreads();
    for (int i = t; i < m; i += 512) {
        int c = col[e0 + i];
        int r = row[e0 + i];
        int p = atomicAdd(&bcur[c >> 8], 1);
        srow[p] = ((c & (BK - 1)) << 17) | r;          // pack (c_local, r); r < 2^17
    }
}

// ---- phase B: per-bucket LDS counting sort; emits off/cnt/dinv AND g1 rows.
// 512 threads: sort phases use all; mm1 split by feature-half across t>>8.
// Offsets are padded to multiples of 4; pad slots hold sentinel NN.
__global__ __launch_bounds__(512) void bucket_sort_mm1_kernel(
        const int* __restrict__ bcursor, int* __restrict__ srow,
        int* __restrict__ off, int* __restrict__ cnt, float* __restrict__ dinv,
        const float* __restrict__ x, const float* __restrict__ W1,
        __half* __restrict__ g1, int n) {
    __shared__ int ebuf[CAP];
    __shared__ int sorted[CAP];
    __shared__ int cnt2[BK];
    __shared__ float sdi[BK];
    __shared__ int wsum[4];
    __shared__ int wbase[4];
    __shared__ int Mtot;
    __shared__ float w1[FIN * FH];
    int t = threadIdx.x;
    for (int i = t; i < FIN * FH; i += 512) w1[i] = W1[i];
    int lo = blockIdx.x << 8;
    int nodes = n - lo; if (nodes > BK) nodes = BK;
    int s0 = blockIdx.x * CAP;
    int m = bcursor[blockIdx.x] - s0;                  // total edges in this bucket
    if (m > CAP) m = CAP;                              // paranoia guard (never hit)
    if (m < 0)  m = 0;
    for (int i = t; i < m; i += 512) ebuf[i] = srow[s0 + i];
    if (t < BK) cnt2[t] = 0;
    __syncthreads();
    for (int i = t; i < m; i += 512) atomicAdd(&cnt2[ebuf[i] >> 17], 1);
    __syncthreads();
    int v = 0, pv = 0, s = 0, excl = 0;
    if (t < BK) {
        v  = cnt2[t];
        pv = (v + 3) & ~3;                             // padded count
        s  = pv;
        #pragma unroll
        for (int d = 1; d < 64; d <<= 1) {             // inclusive wave scan
            int u = __shfl_up(s, d, 64);
            if ((t & 63) >= d) s += u;
        }
        if ((t & 63) == 63) wsum[t >> 6] = s;
    }
    __syncthreads();
    if (t < 4) {
        int b = 0;
        for (int k = 0; k < t; k++) b += wsum[k];
        wbase[t] = b;
    }
    __syncthreads();
    if (t < BK) {
        excl = s + wbase[t >> 6] - pv;                 // exclusive padded prefix
        cnt2[t] = excl;                                // cursor for scatter
        float di = rsqrtf((float)v + 1.0f);
        sdi[t] = di;
        if (t < nodes) {
            off[lo + t]  = s0 + excl;
            cnt[lo + t]  = v;
            dinv[lo + t] = di;
        }
        if (t == BK - 1) Mtot = excl + pv;             // total padded length
    }
    __syncthreads();
    for (int i = t; i < m; i += 512) {
        int pvv = ebuf[i];
        int p = atomicAdd(&cnt2[pvv >> 17], 1);
        sorted[p] = pvv & 0x1FFFF;
    }
    __syncthreads();
    if (t < BK) {                                      // sentinel pads
        for (int p = excl + v; p < excl + pv; p++) sorted[p] = NN;
    }
    __syncthreads();
    int M = Mtot; if (M > CAP) M = CAP;
    for (int i = t; i < M; i += 512) srow[s0 + i] = sorted[i];
    // ---- fused mm1 (split): lane=t>>8 computes feature-half of node t&255 ----
    int lane = t >> 8;                                 // 0 or 1
    int nd0  = t & 255;
    if (nd0 < nodes) {
        int nd = lo + nd0;
        float di = sdi[nd0];
        float xi[FIN];
        const float4* xv = (const float4*)(x + (long long)nd * FIN);
        #pragma unroll
        for (int i = 0; i < FIN / 4; i++) {
            float4 vv = xv[i];
            xi[4*i] = vv.x; xi[4*i+1] = vv.y; xi[4*i+2] = vv.z; xi[4*i+3] = vv.w;
        }
        float h[16];
        #pragma unroll
        for (int j = 0; j < 16; j++) h[j] = 0.f;
        const float* wl = w1 + lane * 16;
        #pragma unroll
        for (int i = 0; i < FIN; i++) {
            float xs = xi[i];
            #pragma unroll
            for (int j = 0; j < 16; j++) h[j] += xs * wl[i * FH + j];
        }
        int4* gv = (int4*)(g1 + (long long)nd * FH) + lane * 2;
        gv[0] = make_int4(pack2(h[0]*di,  h[1]*di),  pack2(h[2]*di,  h[3]*di),
                          pack2(h[4]*di,  h[5]*di),  pack2(h[6]*di,  h[7]*di));
        gv[1] = make_int4(pack2(h[8]*di,  h[9]*di),  pack2(h[10]*di, h[11]*di),
                          pack2(h[12]*di, h[13]*di), pack2(h[14]*di, h[15]*di));
    }
}

// ---- fused gather layer1 (fp16 rows) + relu/bias + mm2 + scale -> g2 (fp16) ----
// block = 256 threads = 64 nodes x 4 lanes (lane = 8 feats = int4 = 16 B).
// Padded CSR: one aligned int4 index load per 4 edges, no tail loop.
constexpr int XS = 36;   // LDS stride: 16B-aligned writes, 2-way (free) reads
__global__ __launch_bounds__(256) void gather_mm2_kernel(
        const int* __restrict__ off, const int* __restrict__ cnt,
        const int* __restrict__ srow, const __half* __restrict__ g1,
        const float* __restrict__ dinv, const float* __restrict__ b1,
        const float* __restrict__ W2, __half* __restrict__ g2, int n) {
    __shared__ float xs[64 * XS];          // 64 nodes x 32 feats (stride 36)
    __shared__ float w[FH * FO];           // 32x16
    __shared__ float bb[FH];
    int t = threadIdx.x;
    for (int i = t; i < FH * FO; i += 256) w[i] = W2[i];
    if (t < FH) bb[t] = b1[t];
    int nl = t >> 2;                       // node-local 0..63
    int q = t & 3;                         // 8-feat group
    int node = blockIdx.x * 64 + nl;
    bool live = node < n;
    float acc[8] = {0.f,0.f,0.f,0.f,0.f,0.f,0.f,0.f};
    float di = 0.f;
    if (live) {
        di = dinv[node];
        {   // self-loop seed
            int4 raw = ((const int4*)(g1 + (long long)node * FH))[q];
            float2 f0 = unpack2(raw.x), f1 = unpack2(raw.y);
            float2 f2 = unpack2(raw.z), f3 = unpack2(raw.w);
            acc[0] = f0.x; acc[1] = f0.y; acc[2] = f1.x; acc[3] = f1.y;
            acc[4] = f2.x; acc[5] = f2.y; acc[6] = f3.x; acc[7] = f3.y;
        }
        int s = off[node];
        int m = cnt[node];
        for (int i = 0; i < m; i += 4) {   // padded: every batch full
            int4 ix = *(const int4*)(srow + s + i);
            int4 ra = ((const int4*)(g1 + (long long)ix.x * FH))[q];
            int4 rb = ((const int4*)(g1 + (long long)ix.y * FH))[q];
            int4 rc = ((const int4*)(g1 + (long long)ix.z * FH))[q];
            int4 rd = ((const int4*)(g1 + (long long)ix.w * FH))[q];
            float2 u;
            u = unpack2(ra.x); acc[0] += u.x; acc[1] += u.y;
            u = unpack2(ra.y); acc[2] += u.x; acc[3] += u.y;
            u = unpack2(ra.z); acc[4] += u.x; acc[5] += u.y;
            u = unpack2(ra.w); acc[6] += u.x; acc[7] += u.y;
            u = unpack2(rb.x); acc[0] += u.x; acc[1] += u.y;
            u = unpack2(rb.y); acc[2] += u.x; acc[3] += u.y;
            u = unpack2(rb.z); acc[4] += u.x; acc[5] += u.y;
            u = unpack2(rb.w); acc[6] += u.x; acc[7] += u.y;
            u = unpack2(rc.x); acc[0] += u.x; acc[1] += u.y;
            u = unpack2(rc.y); acc[2] += u.x; acc[3] += u.y;
            u = unpack2(rc.z); acc[4] += u.x; acc[5] += u.y;
            u = unpack2(rc.w); acc[6] += u.x; acc[7] += u.y;
            u = unpack2(rd.x); acc[0] += u.x; acc[1] += u.y;
            u = unpack2(rd.y); acc[2] += u.x; acc[3] += u.y;
            u = unpack2(rd.z); acc[4] += u.x; acc[5] += u.y;
            u = unpack2(rd.w); acc[6] += u.x; acc[7] += u.y;
        }
    }
    __syncthreads();                       // w/bb loaded; also before xs write
    if (live) {
        // x1[8q..8q+7] = relu(acc*di + b1)
        float* xr = xs + nl * XS + 8 * q;
        #pragma unroll
        for (int j = 0; j < 8; j++) {
            float a = acc[j] * di + bb[8*q + j];
            xr[j] = a > 0.f ? a : 0.f;
        }
    }
    __syncthreads();
    if (live) {
        // lane q computes outputs k = 4q..4q+3 of x1 @ W2 (FO=16)
        const float* xr = xs + nl * XS;
        int k0 = 4 * q;
        float o0 = 0.f, o1 = 0.f, o2 = 0.f, o3 = 0.f;
        #pragma unroll
        for (int j = 0; j < FH; j++) {
            float xj = xr[j];
            const float* wr = w + j * FO + k0;
            o0 += xj * wr[0];
            o1 += xj * wr[1];
            o2 += xj * wr[2];
            o3 += xj * wr[3];
        }
        ((int2*)(g2 + (long long)node * FO))[q] =
            make_int2(pack2(o0 * di, o1 * di), pack2(o2 * di, o3 * di));
    }
}

// ---- fused gather layer2 (fp16 rows) + relu/bias + fc -> out ----
// block = 256 threads = 128 nodes x 2 lanes (lane = 8 feats = int4 = 16 B)
__global__ __launch_bounds__(256) void gather_fc_kernel(
        const int* __restrict__ off, const int* __restrict__ cnt,
        const int* __restrict__ srow, const __half* __restrict__ g2,
        const float* __restrict__ dinv, const float* __restrict__ b2,
        const float* __restrict__ fcW, const float* __restrict__ fcb,
        float* __restrict__ out, int n) {
    __shared__ float w[FO];
    __shared__ float bb[FO];
    __shared__ float fb;
    int t = threadIdx.x;
    if (t < FO) { w[t] = fcW[t]; bb[t] = b2[t]; }
    if (t == 0) fb = fcb[0];
    __syncthreads();
    int node = blockIdx.x * 128 + (t >> 1);
    int q = t & 1;
    if (node >= n) return;
    float di = dinv[node];
    float acc[8];
    {   // self-loop seed
        int4 raw = ((const int4*)(g2 + (long long)node * FO))[q];
        float2 f0 = unpack2(raw.x), f1 = unpack2(raw.y);
        float2 f2 = unpack2(raw.z), f3 = unpack2(raw.w);
        acc[0] = f0.x; acc[1] = f0.y; acc[2] = f1.x; acc[3] = f1.y;
        acc[4] = f2.x; acc[5] = f2.y; acc[6] = f3.x; acc[7] = f3.y;
    }
    int s = off[node];
    int m = cnt[node];
    for (int i = 0; i < m; i += 4) {       // padded: every batch full
        int4 ix = *(const int4*)(srow + s + i);
        int4 ra = ((const int4*)(g2 + (long long)ix.x * FO))[q];
        int4 rb = ((const int4*)(g2 + (long long)ix.y * FO))[q];
        int4 rc = ((const int4*)(g2 + (long long)ix.z * FO))[q];
        int4 rd = ((const int4*)(g2 + (long long)ix.w * FO))[q];
        float2 u;
        u = unpack2(ra.x); acc[0] += u.x; acc[1] += u.y;
        u = unpack2(ra.y); acc[2] += u.x; acc[3] += u.y;
        u = unpack2(ra.z); acc[4] += u.x; acc[5] += u.y;
        u = unpack2(ra.w); acc[6] += u.x; acc[7] += u.y;
        u = unpack2(rb.x); acc[0] += u.x; acc[1] += u.y;
        u = unpack2(rb.y); acc[2] += u.x; acc[3] += u.y;
        u = unpack2(rb.z); acc[4] += u.x; acc[5] += u.y;
        u = unpack2(rb.w); acc[6] += u.x; acc[7] += u.y;
        u = unpack2(rc.x); acc[0] += u.x; acc[1] += u.y;
        u = unpack2(rc.y); acc[2] += u.x; acc[3] += u.y;
        u = unpack2(rc.z); acc[4] += u.x; acc[5] += u.y;
        u = unpack2(rc.w); acc[6] += u.x; acc[7] += u.y;
        u = unpack2(rd.x); acc[0] += u.x; acc[1] += u.y;
        u = unpack2(rd.y); acc[2] += u.x; acc[3] += u.y;
        u = unpack2(rd.z); acc[4] += u.x; acc[5] += u.y;
        u = unpack2(rd.w); acc[6] += u.x; acc[7] += u.y;
    }
    // x2 = relu(acc*di + b2[8q..]); partial dot with fcW
    float p = 0.f;
    #pragma unroll
    for (int j = 0; j < 8; j++) {
        float a = acc[j] * di + bb[8*q + j];
        p += (a > 0.f ? a : 0.f) * w[8*q + j];
    }
    p += __shfl_down(p, 1, 2);             // reduce the node's 2 lanes
    if (q == 0) out[node] = p + fb;
}

extern "C" void kernel_launch(void* const* d_in, const int* in_sizes, int n_in,
                              void* d_out, int out_size, void* d_ws, size_t ws_size,
                              hipStream_t stream) {
    const int*   edge = (const int*)d_in[0];        // [2, E] int32
    const float* x    = (const float*)d_in[1];      // [N, 16]
    const float* W1   = (const float*)d_in[2];      // [16, 32]
    const float* b1   = (const float*)d_in[3];      // [32]
    const float* W2   = (const float*)d_in[4];      // [32, 16]
    const float* b2   = (const float*)d_in[5];      // [16]
    const float* fcW  = (const float*)d_in[6];      // [16, 1]
    const float* fcb  = (const float*)d_in[7];      // [1]
    float* out = (float*)d_out;

    const int E = in_sizes[0] / 2;                  // 1600000
    const int n = NN;
    const int* row = edge;
    const int* col = edge + E;

    // workspace layout (4-byte units), regions 128-elem aligned:
    const size_t nA = (size_t)((n + 127) & ~127);
    char* wsb = (char*)d_ws;
    int*   cnt     = (int*)wsb;                     // n ints (per-node degree)
    int*   off     = cnt + nA;                      // n ints (padded CSR offsets)
    float* dinv    = (float*)(off + nA);            // n floats
    int*   bcursor = (int*)(dinv + nA);             // NBUCKET ints (pad 512)
    int*   srow    = bcursor + 512;                 // (NBUCKET+1)*CAP ints (+slack seg)
    int*   srowEnd = srow + (size_t)(NBUCKET + 1) * CAP;
    __half* g1     = (__half*)srowEnd;              // (n+1)*FH halfs (sentinel row at NN)
    __half* g2     = g1 + (size_t)(n + 1) * FH;     // (n+1)*FO halfs (sentinel row at NN)

    const int nChunkBlocks = (E + CHUNK - 1) / CHUNK;   // 196

    // 1. bcursor[b] = b*CAP; zero sentinel rows
    init_kernel<<<2, 256, 0, stream>>>(bcursor, g1, g2);
    // 2. phase A: bucket fill into fixed segments; per-block run reservation
    bucket_fill_kernel<<<nChunkBlocks, 512, 0, stream>>>(row, col, bcursor, srow, E);
    // 3. phase B: per-bucket LDS counting sort (padded offsets) + fused mm1
    bucket_sort_mm1_kernel<<<NBUCKET, 512, 0, stream>>>(bcursor, srow, off, cnt, dinv, x, W1, g1, n);
    // 4. fused gather1 + relu/bias + mm2 + scale -> g2   (64 nodes/block)
    gather_mm2_kernel<<<(n + 63) / 64, 256, 0, stream>>>(off, cnt, srow, g1, dinv, b1, W2, g2, n);
    // 5. fused gather2 + relu/bias + fc -> out            (128 nodes/block)
    gather_fc_kernel<<<(n + 127) / 128, 256, 0, stream>>>(off, cnt, srow, g2, dinv, b2, fcW, fcb, out, n);
}